// Round 19
// baseline (526.654 us; speedup 1.0000x reference)
//
#include <hip/hip_runtime.h>
#include <hip/hip_bf16.h>

// Problem constants: B=4, S=1024, F=1024, E=8, K=2, H=4*F=4096
constexpr int Ff = 1024;
constexpr int Ee = 8;
constexpr int Hh = 4096;
constexpr int T  = 4096;        // B*S tokens
constexpr int MB = 80;          // 128-row m-units over padded row space (<=10240 rows)

typedef short     bf16x8 __attribute__((ext_vector_type(8)));
typedef float     f32x4  __attribute__((ext_vector_type(4)));
typedef unsigned short u16x8 __attribute__((ext_vector_type(8)));

__device__ __forceinline__ float gelu_fast(float v) {
  const float c2 = 2.0f * 0.7978845608028654f;
  float z2 = c2 * (v + 0.044715f * v * v * v);
  return v / (1.0f + __expf(-z2));
}

__device__ __forceinline__ unsigned short bf16bits(float f) {
  __hip_bfloat16 h = __float2bfloat16(f);
  return *reinterpret_cast<unsigned short*>(&h);
}

__device__ __forceinline__ void gl_lds16(const void* g, void* l) {
  __builtin_amdgcn_global_load_lds(
      (const __attribute__((address_space(1))) unsigned int*)g,
      (__attribute__((address_space(3))) unsigned int*)l, 16, 0, 0);
}

// ------- Gating (fp32, exact routing) + fused last-block prefix -------
__global__ __launch_bounds__(256) void gating_kernel(
    const float* __restrict__ x, const float* __restrict__ Wg,
    const float* __restrict__ bg, int* __restrict__ cnt,
    int* __restrict__ list, float* __restrict__ wlist,
    int* __restrict__ done, int* __restrict__ offs) {
  const int wave = threadIdx.x >> 6;
  const int lane = threadIdx.x & 63;
  const int t = blockIdx.x * 4 + wave;
  float acc[Ee] = {0.f,0.f,0.f,0.f,0.f,0.f,0.f,0.f};
  const float* xrow = x + (size_t)t * Ff;
  for (int f0 = 0; f0 < Ff; f0 += 64) {
    float xv = xrow[f0 + lane];
    const float* wrow = Wg + (size_t)(f0 + lane) * Ee;
    float4 w0 = *reinterpret_cast<const float4*>(wrow);
    float4 w1 = *reinterpret_cast<const float4*>(wrow + 4);
    acc[0] += xv * w0.x; acc[1] += xv * w0.y;
    acc[2] += xv * w0.z; acc[3] += xv * w0.w;
    acc[4] += xv * w1.x; acc[5] += xv * w1.y;
    acc[6] += xv * w1.z; acc[7] += xv * w1.w;
  }
#pragma unroll
  for (int e = 0; e < Ee; ++e) {
#pragma unroll
    for (int off = 32; off; off >>= 1) acc[e] += __shfl_xor(acc[e], off);
  }
  if (lane == 0) {
    float l[Ee], m = -1e30f;
#pragma unroll
    for (int e = 0; e < Ee; ++e) { l[e] = acc[e] + bg[e]; m = fmaxf(m, l[e]); }
    float p[Ee], Z = 0.f;
#pragma unroll
    for (int e = 0; e < Ee; ++e) { p[e] = expf(l[e] - m); Z += p[e]; }
#pragma unroll
    for (int e = 0; e < Ee; ++e) p[e] /= Z;
    int i1 = 0; float p1 = p[0];
#pragma unroll
    for (int e = 1; e < Ee; ++e) if (p[e] > p1) { p1 = p[e]; i1 = e; }
    int i2 = -1; float p2 = -1e30f;
#pragma unroll
    for (int e = 0; e < Ee; ++e) if (e != i1 && p[e] > p2) { p2 = p[e]; i2 = e; }
    float denom = p1 + p2 + 1e-8f;
    int pos = atomicAdd(&cnt[i1], 1);
    list[i1 * T + pos] = t; wlist[i1 * T + pos] = p1 / denom;
    pos = atomicAdd(&cnt[i2], 1);
    list[i2 * T + pos] = t; wlist[i2 * T + pos] = p2 / denom;
  }
  __syncthreads();
  if (threadIdx.x == 0) {
    __threadfence();
    if (atomicAdd(done, 1) == gridDim.x - 1) {
      int s = 0;
#pragma unroll
      for (int e = 0; e < Ee; ++e) {
        offs[e] = s;
        s += (atomicAdd(&cnt[e], 0) + 127) & ~127;
      }
      offs[Ee] = s;
    }
  }
}

// ---- merged pack_w: both W1 chunk and W2 chunk -> packed bf16 units [NB][KT][4][128][8]
__global__ __launch_bounds__(256) void pack_w_kernel(
    const float* __restrict__ src1, unsigned short* __restrict__ dst1,
    int sN1, size_t s_estride1, size_t d_estride1, int KT1v, int NB1,
    const float* __restrict__ src2, unsigned short* __restrict__ dst2,
    int sN2, size_t s_estride2, size_t d_estride2, int KT2v, int NB2,
    int n1) {
  int idx = blockIdx.x;
  const float* src; unsigned short* dst;
  int sN, KT, nb, kt, e;
  size_t s_estride, d_estride;
  if (idx < n1) {
    src = src1; dst = dst1; sN = sN1; KT = KT1v;
    s_estride = s_estride1; d_estride = d_estride1;
    e = idx / (NB1 * KT1v); int r = idx % (NB1 * KT1v);
    nb = r / KT1v; kt = r % KT1v;
  } else {
    idx -= n1;
    src = src2; dst = dst2; sN = sN2; KT = KT2v;
    s_estride = s_estride2; d_estride = d_estride2;
    e = idx / (NB2 * KT2v); int r = idx % (NB2 * KT2v);
    nb = r / KT2v; kt = r % KT2v;
  }
  __shared__ float Ts[128][33];
  const int t = threadIdx.x;
  const float* sb = src + (size_t)e * s_estride + (size_t)(kt * 32) * sN + nb * 128;
  {
    const int row = t >> 5;
    const int cc  = (t & 31) * 4;
#pragma unroll
    for (int i = 0; i < 4; ++i) {
      float4 v = *reinterpret_cast<const float4*>(sb + (size_t)(row + 8 * i) * sN + cc);
      Ts[cc + 0][row + 8 * i] = v.x;
      Ts[cc + 1][row + 8 * i] = v.y;
      Ts[cc + 2][row + 8 * i] = v.z;
      Ts[cc + 3][row + 8 * i] = v.w;
    }
  }
  __syncthreads();
  unsigned short* db = dst + (size_t)e * d_estride + ((size_t)nb * KT + kt) * 4096;
#pragma unroll
  for (int j = 0; j < 2; ++j) {
    const int i2 = t + 256 * j;
    const int col = i2 & 127, kb = i2 >> 7;
    u16x8 o;
#pragma unroll
    for (int q = 0; q < 8; ++q) o[q] = bf16bits(Ts[col][kb * 8 + q]);
    *reinterpret_cast<u16x8*>(db + kb * 1024 + col * 8) = o;
  }
}

// ---- pack_x: gather tokens -> xg[mb][kt][4][128][8], zero-filled pads
__global__ __launch_bounds__(256) void pack_x_kernel(
    const float* __restrict__ x, const int* __restrict__ cnt,
    const int* __restrict__ offs, const int* __restrict__ list,
    unsigned short* __restrict__ xg) {
  const int kt = blockIdx.x;
  const int mb = blockIdx.y;
  const int t = threadIdx.x;
  const int m0g = mb * 128;
  int e = 0;
#pragma unroll
  for (int i = 1; i < Ee; ++i) e += (m0g >= offs[i]) ? 1 : 0;
  const int ce = cnt[e];
  const int row = t >> 1, half = t & 1;
  const int mloc = m0g - offs[e] + row;
  const bool valid = (mloc >= 0) && (mloc < ce);
  const int token = valid ? list[e * T + mloc] : 0;
  const float* sp = x + (size_t)token * Ff + kt * 32 + half * 16;
  u16x8 o0, o1;
#pragma unroll
  for (int i = 0; i < 2; ++i) {
    float4 v = valid ? *reinterpret_cast<const float4*>(sp + i * 4)
                     : make_float4(0.f, 0.f, 0.f, 0.f);
    o0[i * 4 + 0] = bf16bits(v.x); o0[i * 4 + 1] = bf16bits(v.y);
    o0[i * 4 + 2] = bf16bits(v.z); o0[i * 4 + 3] = bf16bits(v.w);
  }
#pragma unroll
  for (int i = 2; i < 4; ++i) {
    float4 v = valid ? *reinterpret_cast<const float4*>(sp + i * 4)
                     : make_float4(0.f, 0.f, 0.f, 0.f);
    o1[(i - 2) * 4 + 0] = bf16bits(v.x); o1[(i - 2) * 4 + 1] = bf16bits(v.y);
    o1[(i - 2) * 4 + 2] = bf16bits(v.z); o1[(i - 2) * 4 + 3] = bf16bits(v.w);
  }
  unsigned short* db = xg + ((size_t)mb * (Ff / 32) + kt) * 4096 + row * 8;
  *reinterpret_cast<u16x8*>(db + (half * 2 + 0) * 1024) = o0;
  *reinterpret_cast<u16x8*>(db + (half * 2 + 1) * 1024) = o1;
}

// ============ GEMM core: A direct global->reg (depth-2, unroll-4), B via LDS depth-3 ============
// Per iteration: wait(group-counted) -> barrier -> 4 B ds_reads -> lgkm0 -> barrier ->
//                A(t+2) reg-loads + B(t+3) stage -> 16 MFMA.
#define LOADA(PA, KT)                                                         \
  _Pragma("unroll")                                                           \
  for (int i_ = 0; i_ < 4; ++i_)                                              \
    PA[i_] = *reinterpret_cast<const bf16x8*>(                                \
        aU + (size_t)(KT) * 4096 + g * 1024 + (wr * 64 + i_ * 16 + r16) * 8);

#define STAGEB(KT)                                                            \
  {                                                                           \
    const unsigned short* bS_ = bU + (size_t)(KT) * 4096 + w * 1024 + lane * 8; \
    unsigned short* bD_ = BsF + ((KT) % 3) * 4096 + w * 1024;                 \
    gl_lds16(bS_,       bD_);                                                 \
    gl_lds16(bS_ + 512, bD_ + 512);                                           \
  }

#define GITER(T, PAU, PAL)                                                    \
  {                                                                           \
    const int t_ = (T);                                                       \
    const int rem_ = NT - t_;                                                 \
    if (t_ == 0 || rem_ == 1) asm volatile("s_waitcnt vmcnt(0)" ::: "memory");\
    else if (rem_ >= 3)       asm volatile("s_waitcnt vmcnt(6)" ::: "memory");\
    else                      asm volatile("s_waitcnt vmcnt(4)" ::: "memory");\
    __builtin_amdgcn_s_barrier();                                             \
    bf16x8 bfr_[4];                                                           \
    const int cb_ = t_ % 3;                                                   \
    _Pragma("unroll")                                                         \
    for (int i_ = 0; i_ < 4; ++i_)                                            \
      bfr_[i_] = *reinterpret_cast<const bf16x8*>(                            \
          BsF + cb_ * 4096 + g * 1024 + (wc * 64 + i_ * 16 + r16) * 8);       \
    asm volatile("s_waitcnt lgkmcnt(0)" ::: "memory");                        \
    __builtin_amdgcn_sched_barrier(0);                                        \
    __builtin_amdgcn_s_barrier();                                             \
    if (t_ + 2 < NT) { LOADA(PAL, t_ + 2) }                                   \
    if (t_ + 3 < NT) STAGEB(t_ + 3)                                           \
    __builtin_amdgcn_s_setprio(1);                                            \
    _Pragma("unroll")                                                         \
    for (int mi_ = 0; mi_ < 4; ++mi_)                                         \
      _Pragma("unroll")                                                       \
      for (int ni_ = 0; ni_ < 4; ++ni_)                                       \
        acc[mi_][ni_] = __builtin_amdgcn_mfma_f32_16x16x32_bf16(              \
            PAU[mi_], bfr_[ni_], acc[mi_][ni_], 0, 0, 0);                     \
    __builtin_amdgcn_s_setprio(0);                                            \
    asm volatile("" ::: "memory");                                            \
  }

#define GEMM_CORE()                                                           \
  f32x4 acc[4][4] = {};                                                       \
  bf16x8 pa0[4], pa1[4], pa2[4], pa3[4];                                      \
  LOADA(pa0, 0)                                                               \
  LOADA(pa1, 1)                                                               \
  STAGEB(0) STAGEB(1) STAGEB(2)                                               \
  _Pragma("unroll 1")                                                         \
  for (int t4 = 0; t4 < NT; t4 += 4) {                                        \
    GITER(t4 + 0, pa0, pa2)                                                   \
    GITER(t4 + 1, pa1, pa3)                                                   \
    GITER(t4 + 2, pa2, pa0)                                                   \
    GITER(t4 + 3, pa3, pa1)                                                   \
  }

// ======== GEMM1: 128^2, 4 waves, A-in-reg + B-LDS depth-3, LDS-coalesced epilogue ========
__global__ __launch_bounds__(256, 3) void gemm1_mfma(
    const unsigned short* __restrict__ xg, const unsigned short* __restrict__ W1P,
    const float* __restrict__ b1, const int* __restrict__ cnt,
    const int* __restrict__ offs, unsigned short* __restrict__ hp, int Hc, int c) {
  const int nxg = Hc >> 7;
  const int nwg = nxg * MB;
  const int raw = blockIdx.x;
  int bid = (raw & 7) * (nwg >> 3) + (raw >> 3);   // XCD gets contiguous range
  const int bw = (nxg >= 4) ? 4 : nxg;             // n-band width
  const int band = bid / (MB * bw);
  const int r2 = bid % (MB * bw);
  const int by = r2 / bw;
  const int bx = band * bw + (r2 % bw);

  const int m0g = by * 128;
  int e = 0;
#pragma unroll
  for (int i = 1; i < Ee; ++i) e += (m0g >= offs[i]) ? 1 : 0;
  const int ce = cnt[e];
  const int mloc = m0g - offs[e];
  if (mloc >= ce) return;
  const int n0 = bx * 128;

  __shared__ __align__(16) unsigned short SMEM[17408];  // max(B bufs 12288, out tile 128x136)
  unsigned short* BsF = SMEM;

  const int tid = threadIdx.x;
  const int w = tid >> 6, lane = tid & 63;
  const int g = lane >> 4, r16 = lane & 15;
  const int wr = w >> 1, wc = w & 1;

  constexpr int NT = Ff / 32;    // 32 packed kt-units
  const unsigned short* aU = xg  + (size_t)by * NT * 4096;
  const unsigned short* bU = W1P + (size_t)(e * nxg + bx) * NT * 4096;

  GEMM_CORE()

  // ---- epilogue: bf16 tile through LDS, then coalesced packed-hp stores ----
  __builtin_amdgcn_s_barrier();
  unsigned short (*Ls)[136] = reinterpret_cast<unsigned short(*)[136]>(SMEM);
#pragma unroll
  for (int ni = 0; ni < 4; ++ni) {
    const int col = wc * 64 + ni * 16 + r16;
    const float bias = b1[(size_t)e * Hh + (size_t)c * Hc + n0 + col];
#pragma unroll
    for (int mi = 0; mi < 4; ++mi)
#pragma unroll
      for (int r = 0; r < 4; ++r) {
        const int row = wr * 64 + mi * 16 + g * 4 + r;
        Ls[row][col] = bf16bits(gelu_fast(acc[mi][ni][r] + bias));
      }
  }
  __builtin_amdgcn_s_barrier();
  unsigned short* hb2 = hp + (size_t)by * (Hc >> 5) * 4096 + (size_t)(n0 >> 5) * 4096;
#pragma unroll
  for (int p = 0; p < 8; ++p) {
    const int u = p * 256 + tid;
    const int oct = u >> 7;
    const int row = u & 127;
    const int lc = oct * 8;
    unsigned short* dst = hb2 + ((size_t)((lc >> 5) * 4 + ((lc >> 3) & 3))) * 1024 + row * 8;
    *reinterpret_cast<u16x8*>(dst) = *reinterpret_cast<const u16x8*>(&Ls[row][lc]);
  }
}

// ==== GEMM2: 128^2, 4 waves, A-in-reg + B-LDS depth-3, ksplit=1, atomic combine ====
__global__ __launch_bounds__(256, 3) void gemm2_mfma(
    const unsigned short* __restrict__ hp, const unsigned short* __restrict__ W2P,
    const float* __restrict__ b2, const int* __restrict__ cnt,
    const int* __restrict__ offs, const int* __restrict__ list,
    const float* __restrict__ wlist, float* __restrict__ out,
    int Hc, int biasC) {
  constexpr int nxg = Ff >> 7;   // 8
  const int nwg = nxg * MB;
  const int raw = blockIdx.x;
  int bid = (raw & 7) * (nwg >> 3) + (raw >> 3);
  const int bx = bid % nxg;      // n fastest -> A-panel reused by co-resident n-blocks
  const int by = bid / nxg;

  const int m0g = by * 128;
  int e = 0;
#pragma unroll
  for (int i = 1; i < Ee; ++i) e += (m0g >= offs[i]) ? 1 : 0;
  const int ce = cnt[e];
  const int mloc = m0g - offs[e];
  if (mloc >= ce) return;
  const int n0 = bx * 128;

  __shared__ __align__(16) unsigned short SMEM[12288];  // 3 x 8KB B bufs
  unsigned short* BsF = SMEM;

  const int tid = threadIdx.x;
  const int w = tid >> 6, lane = tid & 63;
  const int g = lane >> 4, r16 = lane & 15;
  const int wr = w >> 1, wc = w & 1;

  const int KT2 = Hc >> 5;
  const int NT = KT2;            // full K, BK=32 (NT in {8..128}, div by 4)
  const unsigned short* aU = hp  + (size_t)by * KT2 * 4096;
  const unsigned short* bU = W2P + (size_t)(e * nxg + bx) * KT2 * 4096;

  GEMM_CORE()

  const bool addBias = (biasC != 0);
#pragma unroll
  for (int mi = 0; mi < 4; ++mi)
#pragma unroll
    for (int r = 0; r < 4; ++r) {
      const int row = wr * 64 + mi * 16 + g * 4 + r;
      if (mloc + row >= ce) continue;
      const int token = list[e * T + mloc + row];
      const float wgt = wlist[e * T + mloc + row];
      float* op = out + (size_t)token * Ff;
#pragma unroll
      for (int ni = 0; ni < 4; ++ni) {
        const int col = n0 + wc * 64 + ni * 16 + r16;
        float v = acc[mi][ni][r];
        if (addBias) v += b2[(size_t)e * Ff + col];
        atomicAdd(&op[col], wgt * v);
      }
    }
}

extern "C" void kernel_launch(void* const* d_in, const int* in_sizes, int n_in,
                              void* d_out, int out_size, void* d_ws, size_t ws_size,
                              hipStream_t stream) {
  const float* x  = (const float*)d_in[0];
  const float* Wg = (const float*)d_in[1];
  const float* bg = (const float*)d_in[2];
  const float* W1 = (const float*)d_in[3];
  const float* b1 = (const float*)d_in[4];
  const float* W2 = (const float*)d_in[5];
  const float* b2 = (const float*)d_in[6];
  float* out = (float*)d_out;

  const size_t fixed = 1024 + 2 * (size_t)T * Ee * 4 + (size_t)MB * 128 * Ff * 2;
  int Hc = 4096;
  while (Hc > 256 && fixed + (size_t)Hc * 53248 > ws_size) Hc >>= 1;
  const int nchunk = Hh / Hc;

  char* p = (char*)d_ws;
  int*   cnt   = (int*)p;            p += 256;
  int*   done  = (int*)p;            p += 256;
  int*   offs  = (int*)p;            p += 512;
  int*   list  = (int*)p;            p += (size_t)T * Ee * 4;
  float* wlist = (float*)p;          p += (size_t)T * Ee * 4;
  unsigned short* xg  = (unsigned short*)p;  p += (size_t)MB * 128 * Ff * 2;
  unsigned short* W1P = (unsigned short*)p;  p += (size_t)Ee * Hc * Ff * 2;
  unsigned short* W2P = (unsigned short*)p;  p += (size_t)Ee * Ff * Hc * 2;
  unsigned short* hp  = (unsigned short*)p;  // MB*128 x Hc x 2

  hipMemsetAsync(d_out, 0, (size_t)out_size * sizeof(float), stream);
  hipMemsetAsync(cnt, 0, 512, stream);   // cnt + done

  gating_kernel<<<T / 4, 256, 0, stream>>>(x, Wg, bg, cnt, list, wlist, done, offs);
  pack_x_kernel<<<dim3(Ff / 32, MB), 256, 0, stream>>>(x, cnt, offs, list, xg);

  for (int c = 0; c < nchunk; ++c) {
    const int NB1 = Hc / 128, KT1v = Ff / 32;
    const int NB2 = Ff / 128, KT2v = Hc / 32;
    const int n1 = Ee * NB1 * KT1v;
    const int n2 = Ee * NB2 * KT2v;
    pack_w_kernel<<<n1 + n2, 256, 0, stream>>>(
        W1 + (size_t)c * Hc, W1P, Hh, (size_t)Ff * Hh, (size_t)Hc * Ff, KT1v, NB1,
        W2 + (size_t)c * Hc * Ff, W2P, Ff, (size_t)Hh * Ff, (size_t)Ff * Hc, KT2v, NB2,
        n1);
    gemm1_mfma<<<(Hc / 128) * MB, 256, 0, stream>>>(
        xg, W1P, b1, cnt, offs, hp, Hc, c);
    gemm2_mfma<<<(Ff / 128) * MB, 256, 0, stream>>>(
        hp, W2P, b2, cnt, offs, list, wlist, out, Hc,
        c == nchunk - 1 ? 1 : 0);
  }
}

// Round 20
// 434.612 us; speedup vs baseline: 1.2118x; 1.2118x over previous
//
#include <hip/hip_runtime.h>
#include <hip/hip_bf16.h>

// Problem constants: B=4, S=1024, F=1024, E=8, K=2, H=4*F=4096
constexpr int Ff = 1024;
constexpr int Ee = 8;
constexpr int Hh = 4096;
constexpr int T  = 4096;        // B*S tokens
constexpr int MB = 80;          // 128-row m-units over padded row space (<=10240 rows)

typedef short     bf16x8 __attribute__((ext_vector_type(8)));
typedef float     f32x4  __attribute__((ext_vector_type(4)));
typedef unsigned short u16x8 __attribute__((ext_vector_type(8)));

__device__ __forceinline__ float gelu_fast(float v) {
  const float c2 = 2.0f * 0.7978845608028654f;
  float z2 = c2 * (v + 0.044715f * v * v * v);
  return v / (1.0f + __expf(-z2));
}

__device__ __forceinline__ unsigned short bf16bits(float f) {
  __hip_bfloat16 h = __float2bfloat16(f);
  return *reinterpret_cast<unsigned short*>(&h);
}

__device__ __forceinline__ void gl_lds16(const void* g, void* l) {
  __builtin_amdgcn_global_load_lds(
      (const __attribute__((address_space(1))) unsigned int*)g,
      (__attribute__((address_space(3))) unsigned int*)l, 16, 0, 0);
}

// ------- Gating (fp32, exact routing) + fused last-block prefix -------
__global__ __launch_bounds__(256) void gating_kernel(
    const float* __restrict__ x, const float* __restrict__ Wg,
    const float* __restrict__ bg, int* __restrict__ cnt,
    int* __restrict__ list, float* __restrict__ wlist,
    int* __restrict__ done, int* __restrict__ offs) {
  const int wave = threadIdx.x >> 6;
  const int lane = threadIdx.x & 63;
  const int t = blockIdx.x * 4 + wave;
  float acc[Ee] = {0.f,0.f,0.f,0.f,0.f,0.f,0.f,0.f};
  const float* xrow = x + (size_t)t * Ff;
  for (int f0 = 0; f0 < Ff; f0 += 64) {
    float xv = xrow[f0 + lane];
    const float* wrow = Wg + (size_t)(f0 + lane) * Ee;
    float4 w0 = *reinterpret_cast<const float4*>(wrow);
    float4 w1 = *reinterpret_cast<const float4*>(wrow + 4);
    acc[0] += xv * w0.x; acc[1] += xv * w0.y;
    acc[2] += xv * w0.z; acc[3] += xv * w0.w;
    acc[4] += xv * w1.x; acc[5] += xv * w1.y;
    acc[6] += xv * w1.z; acc[7] += xv * w1.w;
  }
#pragma unroll
  for (int e = 0; e < Ee; ++e) {
#pragma unroll
    for (int off = 32; off; off >>= 1) acc[e] += __shfl_xor(acc[e], off);
  }
  if (lane == 0) {
    float l[Ee], m = -1e30f;
#pragma unroll
    for (int e = 0; e < Ee; ++e) { l[e] = acc[e] + bg[e]; m = fmaxf(m, l[e]); }
    float p[Ee], Z = 0.f;
#pragma unroll
    for (int e = 0; e < Ee; ++e) { p[e] = expf(l[e] - m); Z += p[e]; }
#pragma unroll
    for (int e = 0; e < Ee; ++e) p[e] /= Z;
    int i1 = 0; float p1 = p[0];
#pragma unroll
    for (int e = 1; e < Ee; ++e) if (p[e] > p1) { p1 = p[e]; i1 = e; }
    int i2 = -1; float p2 = -1e30f;
#pragma unroll
    for (int e = 0; e < Ee; ++e) if (e != i1 && p[e] > p2) { p2 = p[e]; i2 = e; }
    float denom = p1 + p2 + 1e-8f;
    int pos = atomicAdd(&cnt[i1], 1);
    list[i1 * T + pos] = t; wlist[i1 * T + pos] = p1 / denom;
    pos = atomicAdd(&cnt[i2], 1);
    list[i2 * T + pos] = t; wlist[i2 * T + pos] = p2 / denom;
  }
  __syncthreads();
  if (threadIdx.x == 0) {
    __threadfence();
    if (atomicAdd(done, 1) == gridDim.x - 1) {
      int s = 0;
#pragma unroll
      for (int e = 0; e < Ee; ++e) {
        offs[e] = s;
        s += (atomicAdd(&cnt[e], 0) + 127) & ~127;
      }
      offs[Ee] = s;
    }
  }
}

// ---- merged pack_w: both W1 chunk and W2 chunk -> packed bf16 units [NB][KT][4][128][8]
__global__ __launch_bounds__(256) void pack_w_kernel(
    const float* __restrict__ src1, unsigned short* __restrict__ dst1,
    int sN1, size_t s_estride1, size_t d_estride1, int KT1v, int NB1,
    const float* __restrict__ src2, unsigned short* __restrict__ dst2,
    int sN2, size_t s_estride2, size_t d_estride2, int KT2v, int NB2,
    int n1) {
  int idx = blockIdx.x;
  const float* src; unsigned short* dst;
  int sN, KT, nb, kt, e;
  size_t s_estride, d_estride;
  if (idx < n1) {
    src = src1; dst = dst1; sN = sN1; KT = KT1v;
    s_estride = s_estride1; d_estride = d_estride1;
    e = idx / (NB1 * KT1v); int r = idx % (NB1 * KT1v);
    nb = r / KT1v; kt = r % KT1v;
  } else {
    idx -= n1;
    src = src2; dst = dst2; sN = sN2; KT = KT2v;
    s_estride = s_estride2; d_estride = d_estride2;
    e = idx / (NB2 * KT2v); int r = idx % (NB2 * KT2v);
    nb = r / KT2v; kt = r % KT2v;
  }
  __shared__ float Ts[128][33];
  const int t = threadIdx.x;
  const float* sb = src + (size_t)e * s_estride + (size_t)(kt * 32) * sN + nb * 128;
  {
    const int row = t >> 5;
    const int cc  = (t & 31) * 4;
#pragma unroll
    for (int i = 0; i < 4; ++i) {
      float4 v = *reinterpret_cast<const float4*>(sb + (size_t)(row + 8 * i) * sN + cc);
      Ts[cc + 0][row + 8 * i] = v.x;
      Ts[cc + 1][row + 8 * i] = v.y;
      Ts[cc + 2][row + 8 * i] = v.z;
      Ts[cc + 3][row + 8 * i] = v.w;
    }
  }
  __syncthreads();
  unsigned short* db = dst + (size_t)e * d_estride + ((size_t)nb * KT + kt) * 4096;
#pragma unroll
  for (int j = 0; j < 2; ++j) {
    const int i2 = t + 256 * j;
    const int col = i2 & 127, kb = i2 >> 7;
    u16x8 o;
#pragma unroll
    for (int q = 0; q < 8; ++q) o[q] = bf16bits(Ts[col][kb * 8 + q]);
    *reinterpret_cast<u16x8*>(db + kb * 1024 + col * 8) = o;
  }
}

// ---- pack_x: gather tokens -> xg[mb][kt][4][128][8], zero-filled pads
__global__ __launch_bounds__(256) void pack_x_kernel(
    const float* __restrict__ x, const int* __restrict__ cnt,
    const int* __restrict__ offs, const int* __restrict__ list,
    unsigned short* __restrict__ xg) {
  const int kt = blockIdx.x;
  const int mb = blockIdx.y;
  const int t = threadIdx.x;
  const int m0g = mb * 128;
  int e = 0;
#pragma unroll
  for (int i = 1; i < Ee; ++i) e += (m0g >= offs[i]) ? 1 : 0;
  const int ce = cnt[e];
  const int row = t >> 1, half = t & 1;
  const int mloc = m0g - offs[e] + row;
  const bool valid = (mloc >= 0) && (mloc < ce);
  const int token = valid ? list[e * T + mloc] : 0;
  const float* sp = x + (size_t)token * Ff + kt * 32 + half * 16;
  u16x8 o0, o1;
#pragma unroll
  for (int i = 0; i < 2; ++i) {
    float4 v = valid ? *reinterpret_cast<const float4*>(sp + i * 4)
                     : make_float4(0.f, 0.f, 0.f, 0.f);
    o0[i * 4 + 0] = bf16bits(v.x); o0[i * 4 + 1] = bf16bits(v.y);
    o0[i * 4 + 2] = bf16bits(v.z); o0[i * 4 + 3] = bf16bits(v.w);
  }
#pragma unroll
  for (int i = 2; i < 4; ++i) {
    float4 v = valid ? *reinterpret_cast<const float4*>(sp + i * 4)
                     : make_float4(0.f, 0.f, 0.f, 0.f);
    o1[(i - 2) * 4 + 0] = bf16bits(v.x); o1[(i - 2) * 4 + 1] = bf16bits(v.y);
    o1[(i - 2) * 4 + 2] = bf16bits(v.z); o1[(i - 2) * 4 + 3] = bf16bits(v.w);
  }
  unsigned short* db = xg + ((size_t)mb * (Ff / 32) + kt) * 4096 + row * 8;
  *reinterpret_cast<u16x8*>(db + (half * 2 + 0) * 1024) = o0;
  *reinterpret_cast<u16x8*>(db + (half * 2 + 1) * 1024) = o1;
}

// ======== GEMM1: 128^2, 4 waves, BK=32, depth-3, LDS-coalesced epilogue ========
__global__ __launch_bounds__(256, 3) void gemm1_mfma(
    const unsigned short* __restrict__ xg, const unsigned short* __restrict__ W1P,
    const float* __restrict__ b1, const int* __restrict__ cnt,
    const int* __restrict__ offs, unsigned short* __restrict__ hp, int Hc, int c) {
  const int nxg = Hc >> 7;
  const int nwg = nxg * MB;
  const int raw = blockIdx.x;
  int bid = (raw & 7) * (nwg >> 3) + (raw >> 3);   // XCD gets contiguous range
  const int bw = (nxg >= 4) ? 4 : nxg;             // n-band width
  const int band = bid / (MB * bw);
  const int r2 = bid % (MB * bw);
  const int by = r2 / bw;
  const int bx = band * bw + (r2 % bw);

  const int m0g = by * 128;
  int e = 0;
#pragma unroll
  for (int i = 1; i < Ee; ++i) e += (m0g >= offs[i]) ? 1 : 0;
  const int ce = cnt[e];
  const int mloc = m0g - offs[e];
  if (mloc >= ce) return;
  const int n0 = bx * 128;

  __shared__ __align__(16) unsigned short SMEM[24576];  // 48 KiB
  unsigned short* AsF = SMEM;           // 3 x 4096
  unsigned short* BsF = SMEM + 12288;   // 3 x 4096

  const int tid = threadIdx.x;
  const int w = tid >> 6, lane = tid & 63;
  const int g = lane >> 4, r16 = lane & 15;
  const int wr = w >> 1, wc = w & 1;

  constexpr int NT = Ff / 32;    // 32 packed kt-units
  const unsigned short* aU = xg  + (size_t)by * NT * 4096;
  const unsigned short* bU = W1P + (size_t)(e * nxg + bx) * NT * 4096;

  f32x4 acc[4][4] = {};
  auto STAGE = [&](int buf, int kt) {
    const unsigned short* aS = aU + (size_t)kt * 4096 + w * 1024 + lane * 8;
    const unsigned short* bS = bU + (size_t)kt * 4096 + w * 1024 + lane * 8;
    unsigned short* aD = AsF + buf * 4096 + w * 1024;
    unsigned short* bD = BsF + buf * 4096 + w * 1024;
    gl_lds16(aS,       aD);
    gl_lds16(aS + 512, aD + 512);
    gl_lds16(bS,       bD);
    gl_lds16(bS + 512, bD + 512);
  };
  STAGE(0, 0); STAGE(1, 1); STAGE(2, 2);
  int cur = 0;
#pragma unroll 1
  for (int t = 0; t < NT; ++t) {
    const int rem = NT - t;
    if (rem >= 3)      asm volatile("s_waitcnt vmcnt(8)" ::: "memory");
    else if (rem == 2) asm volatile("s_waitcnt vmcnt(4)" ::: "memory");
    else               asm volatile("s_waitcnt vmcnt(0)" ::: "memory");
    __builtin_amdgcn_s_barrier();
    asm volatile("" ::: "memory");
    bf16x8 af[4], bfr[4];
#pragma unroll
    for (int i = 0; i < 4; ++i) {
      af[i]  = *reinterpret_cast<const bf16x8*>(
          AsF + cur * 4096 + g * 1024 + (wr * 64 + i * 16 + r16) * 8);
      bfr[i] = *reinterpret_cast<const bf16x8*>(
          BsF + cur * 4096 + g * 1024 + (wc * 64 + i * 16 + r16) * 8);
    }
    asm volatile("s_waitcnt lgkmcnt(0)" ::: "memory");
    __builtin_amdgcn_sched_barrier(0);
    __builtin_amdgcn_s_barrier();
    if (t + 3 < NT) STAGE(cur, t + 3);   // (t+3)%3 == cur
    __builtin_amdgcn_s_setprio(1);
#pragma unroll
    for (int mi = 0; mi < 4; ++mi)
#pragma unroll
      for (int ni = 0; ni < 4; ++ni)
        acc[mi][ni] = __builtin_amdgcn_mfma_f32_16x16x32_bf16(
            af[mi], bfr[ni], acc[mi][ni], 0, 0, 0);
    __builtin_amdgcn_s_setprio(0);
    asm volatile("" ::: "memory");
    cur = (cur == 2) ? 0 : cur + 1;
  }
  // ---- epilogue: bf16 tile through LDS, then coalesced packed-hp stores ----
  __builtin_amdgcn_s_barrier();
  unsigned short (*Ls)[136] = reinterpret_cast<unsigned short(*)[136]>(SMEM);
#pragma unroll
  for (int ni = 0; ni < 4; ++ni) {
    const int col = wc * 64 + ni * 16 + r16;
    const float bias = b1[(size_t)e * Hh + (size_t)c * Hc + n0 + col];
#pragma unroll
    for (int mi = 0; mi < 4; ++mi)
#pragma unroll
      for (int r = 0; r < 4; ++r) {
        const int row = wr * 64 + mi * 16 + g * 4 + r;
        Ls[row][col] = bf16bits(gelu_fast(acc[mi][ni][r] + bias));
      }
  }
  __builtin_amdgcn_s_barrier();
  unsigned short* hb2 = hp + (size_t)by * (Hc >> 5) * 4096 + (size_t)(n0 >> 5) * 4096;
#pragma unroll
  for (int p = 0; p < 8; ++p) {
    const int u = p * 256 + tid;
    const int oct = u >> 7;
    const int row = u & 127;
    const int lc = oct * 8;
    unsigned short* dst = hb2 + ((size_t)((lc >> 5) * 4 + ((lc >> 3) & 3))) * 1024 + row * 8;
    *reinterpret_cast<u16x8*>(dst) = *reinterpret_cast<const u16x8*>(&Ls[row][lc]);
  }
}

// ==== GEMM2: 128^2, 4 waves, BK=32, depth-3, ksplit=1 (full K per block) ====
__global__ __launch_bounds__(256, 3) void gemm2_mfma(
    const unsigned short* __restrict__ hp, const unsigned short* __restrict__ W2P,
    const float* __restrict__ b2, const int* __restrict__ cnt,
    const int* __restrict__ offs, const int* __restrict__ list,
    const float* __restrict__ wlist, float* __restrict__ out,
    int Hc, int biasC) {
  constexpr int nxg = Ff >> 7;   // 8
  const int nwg = nxg * MB;
  const int raw = blockIdx.x;
  int bid = (raw & 7) * (nwg >> 3) + (raw >> 3);
  const int bx = bid % nxg;      // n fastest -> A-panel reused by co-resident n-blocks
  const int by = bid / nxg;

  const int m0g = by * 128;
  int e = 0;
#pragma unroll
  for (int i = 1; i < Ee; ++i) e += (m0g >= offs[i]) ? 1 : 0;
  const int ce = cnt[e];
  const int mloc = m0g - offs[e];
  if (mloc >= ce) return;
  const int n0 = bx * 128;

  __shared__ __align__(16) unsigned short AsF[3 * 4096];
  __shared__ __align__(16) unsigned short BsF[3 * 4096];

  const int tid = threadIdx.x;
  const int w = tid >> 6, lane = tid & 63;
  const int g = lane >> 4, r16 = lane & 15;
  const int wr = w >> 1, wc = w & 1;

  const int KT2 = Hc >> 5;
  const int NT = KT2;            // full K, BK=32
  const unsigned short* aU = hp  + (size_t)by * KT2 * 4096;
  const unsigned short* bU = W2P + (size_t)(e * nxg + bx) * KT2 * 4096;

  f32x4 acc[4][4] = {};
  auto STAGE = [&](int buf, int kt) {
    const unsigned short* aS = aU + (size_t)kt * 4096 + w * 1024 + lane * 8;
    const unsigned short* bS = bU + (size_t)kt * 4096 + w * 1024 + lane * 8;
    unsigned short* aD = AsF + buf * 4096 + w * 1024;
    unsigned short* bD = BsF + buf * 4096 + w * 1024;
    gl_lds16(aS,       aD);
    gl_lds16(aS + 512, aD + 512);
    gl_lds16(bS,       bD);
    gl_lds16(bS + 512, bD + 512);
  };
  STAGE(0, 0);
  if (NT > 1) STAGE(1, 1);
  if (NT > 2) STAGE(2, 2);
  int cur = 0;
#pragma unroll 1
  for (int t = 0; t < NT; ++t) {
    const int rem = NT - t;
    if (rem >= 3)      asm volatile("s_waitcnt vmcnt(8)" ::: "memory");
    else if (rem == 2) asm volatile("s_waitcnt vmcnt(4)" ::: "memory");
    else               asm volatile("s_waitcnt vmcnt(0)" ::: "memory");
    __builtin_amdgcn_s_barrier();
    asm volatile("" ::: "memory");
    bf16x8 af[4], bfr[4];
#pragma unroll
    for (int i = 0; i < 4; ++i) {
      af[i]  = *reinterpret_cast<const bf16x8*>(
          AsF + cur * 4096 + g * 1024 + (wr * 64 + i * 16 + r16) * 8);
      bfr[i] = *reinterpret_cast<const bf16x8*>(
          BsF + cur * 4096 + g * 1024 + (wc * 64 + i * 16 + r16) * 8);
    }
    asm volatile("s_waitcnt lgkmcnt(0)" ::: "memory");
    __builtin_amdgcn_sched_barrier(0);
    __builtin_amdgcn_s_barrier();
    if (t + 3 < NT) STAGE(cur, t + 3);
    __builtin_amdgcn_s_setprio(1);
#pragma unroll
    for (int mi = 0; mi < 4; ++mi)
#pragma unroll
      for (int ni = 0; ni < 4; ++ni)
        acc[mi][ni] = __builtin_amdgcn_mfma_f32_16x16x32_bf16(
            af[mi], bfr[ni], acc[mi][ni], 0, 0, 0);
    __builtin_amdgcn_s_setprio(0);
    asm volatile("" ::: "memory");
    cur = (cur == 2) ? 0 : cur + 1;
  }
  const bool addBias = (biasC != 0);
#pragma unroll
  for (int mi = 0; mi < 4; ++mi)
#pragma unroll
    for (int r = 0; r < 4; ++r) {
      const int row = wr * 64 + mi * 16 + g * 4 + r;
      if (mloc + row >= ce) continue;
      const int token = list[e * T + mloc + row];
      const float wgt = wlist[e * T + mloc + row];
      float* op = out + (size_t)token * Ff;
#pragma unroll
      for (int ni = 0; ni < 4; ++ni) {
        const int col = n0 + wc * 64 + ni * 16 + r16;
        float v = acc[mi][ni][r];
        if (addBias) v += b2[(size_t)e * Ff + col];
        atomicAdd(&op[col], wgt * v);
      }
    }
}

extern "C" void kernel_launch(void* const* d_in, const int* in_sizes, int n_in,
                              void* d_out, int out_size, void* d_ws, size_t ws_size,
                              hipStream_t stream) {
  const float* x  = (const float*)d_in[0];
  const float* Wg = (const float*)d_in[1];
  const float* bg = (const float*)d_in[2];
  const float* W1 = (const float*)d_in[3];
  const float* b1 = (const float*)d_in[4];
  const float* W2 = (const float*)d_in[5];
  const float* b2 = (const float*)d_in[6];
  float* out = (float*)d_out;

  const size_t fixed = 1024 + 2 * (size_t)T * Ee * 4 + (size_t)MB * 128 * Ff * 2;
  int Hc = 4096;
  while (Hc > 256 && fixed + (size_t)Hc * 53248 > ws_size) Hc >>= 1;
  const int nchunk = Hh / Hc;

  char* p = (char*)d_ws;
  int*   cnt   = (int*)p;            p += 256;
  int*   done  = (int*)p;            p += 256;
  int*   offs  = (int*)p;            p += 512;
  int*   list  = (int*)p;            p += (size_t)T * Ee * 4;
  float* wlist = (float*)p;          p += (size_t)T * Ee * 4;
  unsigned short* xg  = (unsigned short*)p;  p += (size_t)MB * 128 * Ff * 2;
  unsigned short* W1P = (unsigned short*)p;  p += (size_t)Ee * Hc * Ff * 2;
  unsigned short* W2P = (unsigned short*)p;  p += (size_t)Ee * Ff * Hc * 2;
  unsigned short* hp  = (unsigned short*)p;  // MB*128 x Hc x 2

  hipMemsetAsync(d_out, 0, (size_t)out_size * sizeof(float), stream);
  hipMemsetAsync(cnt, 0, 512, stream);   // cnt + done

  gating_kernel<<<T / 4, 256, 0, stream>>>(x, Wg, bg, cnt, list, wlist, done, offs);
  pack_x_kernel<<<dim3(Ff / 32, MB), 256, 0, stream>>>(x, cnt, offs, list, xg);

  for (int c = 0; c < nchunk; ++c) {
    const int NB1 = Hc / 128, KT1v = Ff / 32;
    const int NB2 = Ff / 128, KT2v = Hc / 32;
    const int n1 = Ee * NB1 * KT1v;
    const int n2 = Ee * NB2 * KT2v;
    pack_w_kernel<<<n1 + n2, 256, 0, stream>>>(
        W1 + (size_t)c * Hc, W1P, Hh, (size_t)Ff * Hh, (size_t)Hc * Ff, KT1v, NB1,
        W2 + (size_t)c * Hc * Ff, W2P, Ff, (size_t)Hh * Ff, (size_t)Ff * Hc, KT2v, NB2,
        n1);
    gemm1_mfma<<<(Hc / 128) * MB, 256, 0, stream>>>(
        xg, W1P, b1, cnt, offs, hp, Hc, c);
    gemm2_mfma<<<(Ff / 128) * MB, 256, 0, stream>>>(
        hp, W2P, b2, cnt, offs, list, wlist, out, Hc,
        c == nchunk - 1 ? 1 : 0);
  }
}